// Round 7
// baseline (3286.646 us; speedup 1.0000x reference)
//
#include <hip/hip_runtime.h>
#include <hip/hip_fp16.h>

// LSTM: 4 layers, T=512, B=256, INPUT=100, H=128, gates=512 (i,f,g,o)
// Round 6:
//  - Diagnosis history: rounds 1-5 showed the allocator places per-thread
//    weight arrays in AGPRs (VGPR_Count 88 + hidden AGPRs) and gfx950 VALU
//    cannot read AGPR sources (round-5 assembler error proves it) -> every
//    weight use = v_accvgpr_read + v_fmac: ~460 VALU/thread/step, scan is
//    VALU-issue-bound.
//  - Fix: Whh packed to f16 pairs (prep kernel), inner product via
//    __builtin_amdgcn_fdot2 (v_dot2_f32_f16, 2 MACs/inst, fp32 accum):
//    64 dot2 replaces 128 fma + 128 mov. Weight state = 64 dwords ("+v"
//    pinned). h kept in LDS as f16 (slices at 80B stride: conflict-free).
//    Precision: preact err ~3e-4, output err ~1e-3 < 2.35e-3 threshold.
//  - gemm_xg (fp32) / fc unchanged.
// ws: io [512*256*128]f32 @0 (67MB) | xg [64*256*512]f32 @67MB (33.5MB)
//     | hstate,cstate f32 @100.66MB (256KB) | wh16 @ +256KB (512KB) => ~101.4MB

#define TSTEPS 512
#define BATCH  256
#define HID    128
#define GATES  512
#define TC     64

typedef _Float16 v2h __attribute__((ext_vector_type(2)));

__device__ __forceinline__ v2h as_h2(unsigned int u) {
    return __builtin_bit_cast(v2h, u);
}

__device__ __forceinline__ float sigmoid_f(float x) {
    return 1.0f / (1.0f + __expf(-x));
}
__device__ __forceinline__ float tanh_f(float x) {
    float e = __expf(2.0f * x);
    return 1.0f - 2.0f / (e + 1.0f);
}

// quad butterfly sum via DPP: xor1 = quad_perm[1,0,3,2] (0xB1),
// xor2 = quad_perm[2,3,0,1] (0x4E). Pure VALU, no LDS pipe.
__device__ __forceinline__ float quad_sum(float v) {
    int b = __builtin_amdgcn_mov_dpp(__float_as_int(v), 0xB1, 0xF, 0xF, true);
    float s = v + __int_as_float(b);
    int c = __builtin_amdgcn_mov_dpp(__float_as_int(s), 0x4E, 0xF, 0xF, true);
    return s + __int_as_float(c);
}

// ---------------- Whh f16 pack ----------------
// wh16[l][tid=512][g=4][d=16] (dwords): pack(Whh_l[g*128+q][32p+2d], [..+1])
// where tid = q*4+p. One-time prep; 131072 threads.
__global__ __launch_bounds__(256)
void pack_whh(const float* __restrict__ W0, const float* __restrict__ W1,
              const float* __restrict__ W2, const float* __restrict__ W3,
              unsigned int* __restrict__ out)
{
    int F = blockIdx.x * 256 + threadIdx.x;      // [0, 131072)
    int l = F >> 15;
    int r = F & 32767;
    int tid_s = r >> 6;
    int g = (r >> 4) & 3;
    int d = r & 15;
    int q = tid_s >> 2, p = tid_s & 3;
    const float* W = (l == 0) ? W0 : (l == 1) ? W1 : (l == 2) ? W2 : W3;
    const float* src = W + (g * HID + q) * HID + p * 32 + 2 * d;
    __half2 hh = __floats2half2_rn(src[0], src[1]);
    out[F] = __builtin_bit_cast(unsigned int, hh);
}

// ---------------- input-projection GEMM ----------------
// XG[r, j] = A[row r, :]·W[j, :] + b_ih[j] + b_hh[j]  (fp32)
template<int K, bool L0>
__global__ __launch_bounds__(256, 4)
void gemm_xg(const float* __restrict__ A, const float* __restrict__ W,
             const float* __restrict__ bih, const float* __restrict__ bhh,
             float* __restrict__ XG, int t0)
{
    __shared__ float As[32][68];  // As[kk][row]
    __shared__ float Bs[32][68];  // Bs[kk][col]
    const int tid  = threadIdx.x;
    const int flat = blockIdx.y * 8 + blockIdx.x;   // [0,2048)
    const int rt   = flat & 255;   // row tile
    const int ct   = flat >> 8;    // col tile 0..7
    const int j0   = ct * 64;
    const int R0   = rt * 64;
    const int ty = tid >> 4, tx = tid & 15;

    float acc[4][4] = {};

    for (int kt = 0; kt < K; kt += 32) {
        #pragma unroll
        for (int i = 0; i < 8; ++i) {
            int f  = tid + 256 * i;
            int r  = f >> 5, kk = f & 31;
            int k  = kt + kk;
            int Rg = R0 + r;
            int q  = Rg >> 8, b = Rg & 255;
            float av = 0.f, wv = 0.f;
            if (K == 128 || k < K) {
                av = L0 ? A[(b * TSTEPS + (t0 + q)) * K + k]
                        : A[((t0 + q) * BATCH + b) * K + k];
                wv = W[(j0 + r) * K + k];
            }
            As[kk][r] = av;
            Bs[kk][r] = wv;
        }
        __syncthreads();
        #pragma unroll 8
        for (int kk = 0; kk < 32; ++kk) {
            float4 a4 = *(const float4*)&As[kk][ty * 4];
            float4 b4 = *(const float4*)&Bs[kk][tx * 4];
            float aa[4] = {a4.x, a4.y, a4.z, a4.w};
            float bb[4] = {b4.x, b4.y, b4.z, b4.w};
            #pragma unroll
            for (int ii = 0; ii < 4; ++ii)
                #pragma unroll
                for (int jj = 0; jj < 4; ++jj)
                    acc[ii][jj] = fmaf(aa[ii], bb[jj], acc[ii][jj]);
        }
        __syncthreads();
    }

    float4 bi = *(const float4*)&bih[j0 + tx * 4];
    float4 bh = *(const float4*)&bhh[j0 + tx * 4];
    float bsum[4] = {bi.x + bh.x, bi.y + bh.y, bi.z + bh.z, bi.w + bh.w};
    #pragma unroll
    for (int ii = 0; ii < 4; ++ii) {
        int Rg = R0 + ty * 4 + ii;
        float4 st = {acc[ii][0] + bsum[0], acc[ii][1] + bsum[1],
                     acc[ii][2] + bsum[2], acc[ii][3] + bsum[3]};
        *(float4*)&XG[Rg * GATES + j0 + tx * 4] = st;
    }
}

// ---------------- recurrent scan ----------------
// One block (512 thr) per batch row. Thread (q = tid>>2, p = tid&3) owns all
// 4 gates of hidden unit q over k-slice [32p,32p+32). Weights: 64 f16x2
// dwords in VGPRs, consumed by v_dot2_f32_f16. h in LDS as f16 (slice p at
// dword 20p: bases mod-32 banks {0,20,8,28} -> conflict-free 16B reads).
__global__ __attribute__((amdgpu_waves_per_eu(2, 2))) __launch_bounds__(512)
void lstm_rec(const float* __restrict__ XG, const unsigned int* __restrict__ WH16,
              float* __restrict__ Hout,
              float* __restrict__ hstate, float* __restrict__ cstate,
              int t0, int first)
{
    const int b   = blockIdx.x;
    const int tid = threadIdx.x;
    const int q   = tid >> 2;   // hidden unit 0..127
    const int p   = tid & 3;    // k-slice 0..3
    __shared__ unsigned int hbuf[2][80];  // 160 halfs: unit u at half (u>>5)*40+(u&31)

    // 64 packed f16x2 weights: wq[g*16+d] = Whh[g*128+q][32p+2d .. +1]
    unsigned int wq[64];
    {
        const uint4* wp4 = (const uint4*)(WH16 + (size_t)tid * 64);
        #pragma unroll
        for (int i = 0; i < 16; ++i) {
            uint4 v = wp4[i];
            wq[4 * i + 0] = v.x; wq[4 * i + 1] = v.y;
            wq[4 * i + 2] = v.z; wq[4 * i + 3] = v.w;
        }
    }
    #pragma unroll
    for (int i = 0; i < 64; ++i)
        asm volatile("" : "+v"(wq[i]));   // keep opaque: no remat

    float c;
    float h0 = 0.f;
    if (first) {
        c = 0.f;
    } else {
        c  = cstate[b * HID + q];
        h0 = hstate[b * HID + q];
    }
    if (p == 0) {
        __half* hb = (__half*)&hbuf[0][0];
        hb[(q >> 5) * 40 + (q & 31)] = __float2half_rn(h0);
    }
    __syncthreads();

    // lane p streams gate p's xg for unit q
    const float* xgp = XG + b * GATES + p * HID + q;
    float xg_val = xgp[0];
    float h = 0.f;
    int cur = 0;
    for (int s = 0; s < TC; ++s) {
        float xg_next = 0.f;
        if (s + 1 < TC) xg_next = xgp[(s + 1) * (BATCH * GATES)];

        float g0 = (p == 0) ? xg_val : 0.f;
        float g1 = (p == 1) ? xg_val : 0.f;
        float g2 = (p == 2) ? xg_val : 0.f;
        float g3 = (p == 3) ? xg_val : 0.f;
        #pragma unroll
        for (int j = 0; j < 4; ++j) {
            // 8 halfs = units [32p+8j, +8): dwords (pairs) 4j..4j+3
            uint4 hv = *(const uint4*)&hbuf[cur][p * 20 + 4 * j];
            v2h h2;
            h2 = as_h2(hv.x);
            g0 = __builtin_amdgcn_fdot2(as_h2(wq[0*16+4*j+0]), h2, g0, false);
            g1 = __builtin_amdgcn_fdot2(as_h2(wq[1*16+4*j+0]), h2, g1, false);
            g2 = __builtin_amdgcn_fdot2(as_h2(wq[2*16+4*j+0]), h2, g2, false);
            g3 = __builtin_amdgcn_fdot2(as_h2(wq[3*16+4*j+0]), h2, g3, false);
            h2 = as_h2(hv.y);
            g0 = __builtin_amdgcn_fdot2(as_h2(wq[0*16+4*j+1]), h2, g0, false);
            g1 = __builtin_amdgcn_fdot2(as_h2(wq[1*16+4*j+1]), h2, g1, false);
            g2 = __builtin_amdgcn_fdot2(as_h2(wq[2*16+4*j+1]), h2, g2, false);
            g3 = __builtin_amdgcn_fdot2(as_h2(wq[3*16+4*j+1]), h2, g3, false);
            h2 = as_h2(hv.z);
            g0 = __builtin_amdgcn_fdot2(as_h2(wq[0*16+4*j+2]), h2, g0, false);
            g1 = __builtin_amdgcn_fdot2(as_h2(wq[1*16+4*j+2]), h2, g1, false);
            g2 = __builtin_amdgcn_fdot2(as_h2(wq[2*16+4*j+2]), h2, g2, false);
            g3 = __builtin_amdgcn_fdot2(as_h2(wq[3*16+4*j+2]), h2, g3, false);
            h2 = as_h2(hv.w);
            g0 = __builtin_amdgcn_fdot2(as_h2(wq[0*16+4*j+3]), h2, g0, false);
            g1 = __builtin_amdgcn_fdot2(as_h2(wq[1*16+4*j+3]), h2, g1, false);
            g2 = __builtin_amdgcn_fdot2(as_h2(wq[2*16+4*j+3]), h2, g2, false);
            g3 = __builtin_amdgcn_fdot2(as_h2(wq[3*16+4*j+3]), h2, g3, false);
        }
        // quad butterfly (DPP, VALU-only): all 4 p-lanes get full i,f,g,o
        g0 = quad_sum(g0);
        g1 = quad_sum(g1);
        g2 = quad_sum(g2);
        g3 = quad_sum(g3);

        c = sigmoid_f(g1) * c + sigmoid_f(g0) * tanh_f(g2);
        h = sigmoid_f(g3) * tanh_f(c);

        if (p == 0) {
            __half* hb = (__half*)&hbuf[cur ^ 1][0];
            hb[(q >> 5) * 40 + (q & 31)] = __float2half_rn(h);
            Hout[((t0 + s) * BATCH + b) * HID + q] = h;
        }
        __syncthreads();
        cur ^= 1;
        xg_val = xg_next;
    }
    if (p == 0) {
        hstate[b * HID + q] = h;
        cstate[b * HID + q] = c;
    }
}

// ---------------- final FC ----------------
__global__ __launch_bounds__(512)
void fc_kernel(const float* __restrict__ hstate, const float* __restrict__ fcw,
               const float* __restrict__ fcb, float* __restrict__ out)
{
    int idx = threadIdx.x;      // 512 = 256 rows x 2 outs
    int b = idx >> 1, o = idx & 1;
    float acc = fcb[o];
    #pragma unroll
    for (int k = 0; k < HID; ++k)
        acc = fmaf(hstate[b * HID + k], fcw[o * HID + k], acc);
    out[b * 2 + o] = acc;
}

extern "C" void kernel_launch(void* const* d_in, const int* in_sizes, int n_in,
                              void* d_out, int out_size, void* d_ws, size_t ws_size,
                              hipStream_t stream)
{
    const float* x = (const float*)d_in[0];
    const float* w_ih[4]; const float* w_hh[4];
    const float* b_ih[4]; const float* b_hh[4];
    for (int l = 0; l < 4; ++l) {
        w_ih[l] = (const float*)d_in[1 + 4 * l];
        w_hh[l] = (const float*)d_in[2 + 4 * l];
        b_ih[l] = (const float*)d_in[3 + 4 * l];
        b_hh[l] = (const float*)d_in[4 + 4 * l];
    }
    const float* fc_w = (const float*)d_in[17];
    const float* fc_b = (const float*)d_in[18];
    float* out = (float*)d_out;

    char* wsb = (char*)d_ws;
    float* io  = (float*)wsb;                                   // 67,108,864 B
    float* xg  = (float*)(wsb + 67108864);                      // 33,554,432 B
    float* hst = (float*)(wsb + 67108864 + 33554432);           // 131,072 B
    float* cst = hst + BATCH * HID;                             // 131,072 B
    unsigned int* wh16 = (unsigned int*)(wsb + 67108864 + 33554432 + 262144); // 524,288 B

    // one-time f16 pack of all 4 Whh
    pack_whh<<<512, 256, 0, stream>>>(w_hh[0], w_hh[1], w_hh[2], w_hh[3], wh16);

    dim3 ggrid(8, 256);  // x = col tile (fast), y = row tile
    for (int l = 0; l < 4; ++l) {
        const unsigned int* whl = wh16 + (size_t)l * 512 * 64;
        for (int cchunk = 0; cchunk < TSTEPS / TC; ++cchunk) {
            int t0 = cchunk * TC;
            if (l == 0)
                gemm_xg<100, true><<<ggrid, 256, 0, stream>>>(x, w_ih[0], b_ih[0], b_hh[0], xg, t0);
            else
                gemm_xg<128, false><<<ggrid, 256, 0, stream>>>(io, w_ih[l], b_ih[l], b_hh[l], xg, t0);
            lstm_rec<<<256, 512, 0, stream>>>(xg, whl, io, hst, cst, t0, cchunk == 0 ? 1 : 0);
        }
    }
    fc_kernel<<<1, 512, 0, stream>>>(hst, fc_w, fc_b, out);
}